// Round 1
// baseline (250.349 us; speedup 1.0000x reference)
//
#include <hip/hip_runtime.h>

// IndRNN, 2 layers, diagonal recurrence:
//   layer l: h[t] = relu(x[t] + w_l * h[t-1])   (elementwise over B*H chains)
// Fully fused: layer-1 output stays in registers; one pass over x, one write of out.
// x: [T=2048, B=32, H=512] fp32; w_hh: [2, 512]; h0: [2, 32, 512] (zeros).
//
// Mapping: 1 thread = 1 (b,h) chain. 16384 chains -> grid=256 blocks x 64 threads
// so all 256 CUs host one wave each (block=256 would use only 64 CUs).
// Latency hiding at 1 wave/CU: ping-pong register prefetch, 32 loads in flight.

#define TSTEPS 2048
#define BATCH  32
#define HID    512
#define BH     (BATCH * HID)      /* 16384 chains */
#define UNROLL 32
#define NBLK   (TSTEPS / UNROLL)  /* 64 */

__global__ __launch_bounds__(64, 1) void indrnn_fused_kernel(
    const float* __restrict__ x,
    const float* __restrict__ w_hh,
    const float* __restrict__ h0,
    float* __restrict__ out) {
  const int c   = blockIdx.x * 64 + threadIdx.x;  // chain id in [0, BH)
  const int hid = c & (HID - 1);

  const float w1 = w_hh[hid];
  const float w2 = w_hh[HID + hid];
  float h1 = h0[c];
  float h2 = h0[BH + c];

  const float* xp = x + c;
  float*       op = out + c;

  float bufA[UNROLL], bufB[UNROLL];

  // Prologue: loads for block 0.
#pragma unroll
  for (int u = 0; u < UNROLL; ++u)
    bufA[u] = xp[(size_t)u * BH];

  for (int blk = 0; blk < NBLK; blk += 2) {
    // Issue loads for blk+1 (always exists: NBLK even).
    {
      const float* xn = xp + (size_t)(blk + 1) * UNROLL * BH;
#pragma unroll
      for (int u = 0; u < UNROLL; ++u)
        bufB[u] = xn[(size_t)u * BH];
    }
    // Compute blk from bufA.
    {
      float* ob = op + (size_t)blk * UNROLL * BH;
#pragma unroll
      for (int u = 0; u < UNROLL; ++u) {
        h1 = fmaxf(fmaf(w1, h1, bufA[u]), 0.0f);
        h2 = fmaxf(fmaf(w2, h2, h1), 0.0f);
        __builtin_nontemporal_store(h2, ob + (size_t)u * BH);
      }
    }
    // Issue loads for blk+2.
    if (blk + 2 < NBLK) {
      const float* xn = xp + (size_t)(blk + 2) * UNROLL * BH;
#pragma unroll
      for (int u = 0; u < UNROLL; ++u)
        bufA[u] = xn[(size_t)u * BH];
    }
    // Compute blk+1 from bufB.
    {
      float* ob = op + (size_t)(blk + 1) * UNROLL * BH;
#pragma unroll
      for (int u = 0; u < UNROLL; ++u) {
        h1 = fmaxf(fmaf(w1, h1, bufB[u]), 0.0f);
        h2 = fmaxf(fmaf(w2, h2, h1), 0.0f);
        __builtin_nontemporal_store(h2, ob + (size_t)u * BH);
      }
    }
  }
}

extern "C" void kernel_launch(void* const* d_in, const int* in_sizes, int n_in,
                              void* d_out, int out_size, void* d_ws, size_t ws_size,
                              hipStream_t stream) {
  const float* x    = (const float*)d_in[0];
  const float* w_hh = (const float*)d_in[1];
  const float* h0   = (const float*)d_in[2];
  float* out        = (float*)d_out;

  dim3 grid(BH / 64);  // 256 blocks -> 1 wave per CU across all 256 CUs
  dim3 block(64);
  hipLaunchKernelGGL(indrnn_fused_kernel, grid, block, 0, stream,
                     x, w_hh, h0, out);
}

// Round 2
// 243.526 us; speedup vs baseline: 1.0280x; 1.0280x over previous
//
#include <hip/hip_runtime.h>

// IndRNN, 2 layers, diagonal recurrence: h[t] = relu(x[t] + w*h[t-1]) per layer,
// fused (layer-1 output never touches memory).
// x: [T=2048, B=32, H=512] fp32. 16384 independent chains -> 256 waves, 1/CU.
//
// R2 change vs R1: (a) regular stores (ack at L2, ~200cy) instead of nontemporal
// (ack at HBM, ~900cy) so the vmcnt FIFO drains; (b) 4-deep x 16-wide register
// load pipeline (48 loads in flight, issued 3 blocks ahead) with static buffer
// indices (blk loop unrolled by D) so buf[] stays in VGPRs.

#define TSTEPS 2048
#define BATCH  32
#define HID    512
#define BH     (BATCH * HID)   /* 16384 chains */
#define U      16              /* elements per block */
#define D      4               /* pipeline depth (buffers) */
#define NBLK   (TSTEPS / U)    /* 128, divisible by D */

__global__ __launch_bounds__(64, 1) void indrnn_fused_kernel(
    const float* __restrict__ x,
    const float* __restrict__ w_hh,
    const float* __restrict__ h0,
    float* __restrict__ out) {
  const int c   = blockIdx.x * 64 + threadIdx.x;  // chain id
  const int hid = c & (HID - 1);

  const float w1 = w_hh[hid];
  const float w2 = w_hh[HID + hid];
  float h1 = h0[c];
  float h2 = h0[BH + c];

  const float* xp = x + c;
  float*       op = out + c;

  float buf[D][U];

  // Prologue: fill buffers for blocks 0..D-2 (48 loads in flight).
#pragma unroll
  for (int d = 0; d < D - 1; ++d) {
    const float* xn = xp + (size_t)d * U * BH;
#pragma unroll
    for (int u = 0; u < U; ++u)
      buf[d][u] = xn[(size_t)u * BH];
  }

  for (int blk0 = 0; blk0 < NBLK; blk0 += D) {
#pragma unroll
    for (int d = 0; d < D; ++d) {
      const int blk  = blk0 + d;
      const int pblk = blk + (D - 1);      // block to prefetch
      if (pblk < NBLK) {
        const float* xn = xp + (size_t)pblk * U * BH;
#pragma unroll
        for (int u = 0; u < U; ++u)
          buf[(d + D - 1) & (D - 1)][u] = xn[(size_t)u * BH];
      }
      float* ob = op + (size_t)blk * U * BH;
#pragma unroll
      for (int u = 0; u < U; ++u) {
        h1 = fmaxf(fmaf(w1, h1, buf[d][u]), 0.0f);
        h2 = fmaxf(fmaf(w2, h2, h1), 0.0f);
        ob[(size_t)u * BH] = h2;   // regular store: acks at L2, keeps vmcnt FIFO short
      }
    }
  }
}

extern "C" void kernel_launch(void* const* d_in, const int* in_sizes, int n_in,
                              void* d_out, int out_size, void* d_ws, size_t ws_size,
                              hipStream_t stream) {
  const float* x    = (const float*)d_in[0];
  const float* w_hh = (const float*)d_in[1];
  const float* h0   = (const float*)d_in[2];
  float* out        = (float*)d_out;

  dim3 grid(BH / 64);   // 256 blocks x 64 threads: one wave per CU
  dim3 block(64);
  hipLaunchKernelGGL(indrnn_fused_kernel, grid, block, 0, stream,
                     x, w_hh, h0, out);
}